// Round 23
// baseline (1513.805 us; speedup 1.0000x reference)
//
#include <hip/hip_runtime.h>
#include <math.h>

// Problem constants
#define F_DIM 321
#define H_DIM 4200
#define T_DIM 1000
#define NBC   16      // B*C = 8*2
#define KTOP  3
#define PADV  1e-8f

// r23 = r22's proven A-in-SGPR dbuf + r21's R=16 reuse geometry.
// r22 (R=8): VALUBusy 58%, B delivery 64 B/cyc/CU == L1 ceiling -> stuck.
// Now: wave owns 16 rows x 128 cols; lane owns 16r x 2c (acc=32); B demand
// halves to 32 B/cyc/CU. 2-k groups keep the A double-buffer at 2x32 = 64
// SGPRs (4-k would need 128 > budget). Zero-LDS, zero-barrier main loop.
#define BM 64         // h rows per block tile (4 waves x 16)
#define BN 128        // t cols per block tile (64 lanes x 2)
#define NRT 66        // ceil(H_DIM / BM)
#define NG  160       // 2-k groups covering k=0..319 (tail k=320 separate)
#define NTT 8         // ceil(T_DIM / BN)

typedef float v2f __attribute__((ext_vector_type(2)));

__device__ __forceinline__ void ins3(float v, int i,
                                     float& v0, float& v1, float& v2,
                                     int& i0, int& i1, int& i2) {
  // strict '>' keeps earlier (smaller-h) entries ahead on ties == lax.top_k
  if (v > v0)      { v2 = v1; i2 = i1; v1 = v0; i1 = i0; v0 = v; i0 = i; }
  else if (v > v1) { v2 = v1; i2 = i1; v1 = v;  i1 = i; }
  else if (v > v2) { v2 = v;  i2 = i; }
}

// load one 2-k B group (2 k-rows x 2 cols/lane) into 2 named v2f regs
#define LOADB(B0, B1, g) do {                                          \
    const float* _p = pB + (size_t)((g) * 2) * T_DIM;                  \
    B0 = *(const v2f*)(_p);                                            \
    B1 = *(const v2f*)(_p + T_DIM);                                    \
  } while (0)

// load one 2-k A group (16 rows x 2 k, wave-uniform -> SGPR) into array D
#define LOADA(D, g) do {                                               \
    _Pragma("unroll") for (int r = 0; r < 16; ++r)                     \
      _Pragma("unroll") for (int q = 0; q < 2; ++q)                    \
        D[r][q] = im[ab[r] + (g) * 2 + q];                             \
  } while (0)

// FMA one 2-k group from pre-loaded A (k ascending per acc element)
#define FMAG(B0, B1, A) do {                                           \
    _Pragma("unroll") for (int r = 0; r < 16; ++r)                     \
      _Pragma("unroll") for (int c = 0; c < 2; ++c) {                  \
        acc[r][c] = fmaf(A[r][0], B0[c], acc[r][c]);                   \
        acc[r][c] = fmaf(A[r][1], B1[c], acc[r][c]);                   \
      }                                                                \
  } while (0)

// K1: fused fp32 GEMM (nominee = integral_m @ mag[bc]) + running top-3 over h.
__global__ __launch_bounds__(256)
void hi_k1_gemm_top3(const float* __restrict__ mag,
                     const float* __restrict__ im,
                     float* __restrict__ wv, int* __restrict__ wi,
                     int nsplit) {
  const int tid  = threadIdx.x;
  const int lane = tid & 63;
  const int w    = tid >> 6;      // wave index 0..3
  const int t0 = blockIdx.x * BN;
  const int bc = blockIdx.y;
  const int sp = blockIdx.z;
  const int rt_begin = (sp * NRT) / nsplit;
  const int rt_end   = ((sp + 1) * NRT) / nsplit;

  __shared__ float mv[4 * BN * KTOP];   // merge scratch only (6 KB)
  __shared__ int   mi[4 * BN * KTOP];   // (6 KB)

  const float* magbc = mag + (size_t)bc * F_DIM * T_DIM;
  const float* pB = magbc + t0 + lane * 2;   // per-lane B column base
  // (t overrun of the last t-tile reads into the next k-row: in-bounds for
  //  k<=319 [max addr 319*1000+1023 < 321000]; those columns are discarded
  //  at store time. k=320 tail is guarded.)

  float gv0 = -INFINITY, gv1 = -INFINITY, gv2 = -INFINITY;
  int   gi0 = 0, gi1 = 0, gi2 = 0;

  for (int rt = rt_begin; rt < rt_end; ++rt) {
    const int h0 = rt * BM;
    // wave-uniform row bases (SGPR); clamp dups masked at top-3
    int ab[16];
#pragma unroll
    for (int r = 0; r < 16; ++r) {
      int gh = h0 + w * 16 + r;
      if (gh >= H_DIM) gh = H_DIM - 1;
      ab[r] = __builtin_amdgcn_readfirstlane(gh * F_DIM);
    }

    float acc[16][2];
#pragma unroll
    for (int r = 0; r < 16; ++r) { acc[r][0] = 0.f; acc[r][1] = 0.f; }

    float Ac[16][2], An[16][2];
    v2f Bc0, Bc1, Bn0, Bn1;
    LOADA(Ac, 0);
    LOADB(Bc0, Bc1, 0);

    // 80 double-steps cover g=0..159 (k=0..319). Both operands register-
    // double-buffered one group ahead; no LDS, no barriers in the k-loop.
#pragma unroll 1
    for (int gs = 0; gs < NG / 2; ++gs) {
      const int ge = 2 * gs, go = 2 * gs + 1;
      LOADA(An, go);
      LOADB(Bn0, Bn1, go);                    // go <= 159 always
      FMAG(Bc0, Bc1, Ac);
      if (ge + 2 < NG) {
        LOADA(Ac, ge + 2);
        LOADB(Bc0, Bc1, ge + 2);
      }
      FMAG(Bn0, Bn1, An);
    }

    // K tail: k = 320 (single column), guarded loads
    {
      float bt[2];
#pragma unroll
      for (int c = 0; c < 2; ++c) {
        int gt = t0 + lane * 2 + c;
        bt[c] = (gt < T_DIM) ? magbc[(size_t)(F_DIM - 1) * T_DIM + gt] : 0.f;
      }
#pragma unroll
      for (int r = 0; r < 16; ++r) {
        float av = im[ab[r] + (F_DIM - 1)];
        acc[r][0] = fmaf(av, bt[0], acc[r][0]);
        acc[r][1] = fmaf(av, bt[1], acc[r][1]);
      }
    }

    // thread-local top-3 per column over own 16 rows (h ascending); wave
    // bands ascend in w, so cross-wave merge preserves lax.top_k tie order.
#pragma unroll
    for (int c = 0; c < 2; ++c) {
      const int col = lane * 2 + c;
      float v0 = -INFINITY, v1 = -INFINITY, v2 = -INFINITY;
      int   i0 = 0, i1 = 0, i2 = 0;
#pragma unroll
      for (int r = 0; r < 16; ++r) {
        int gh = h0 + w * 16 + r;
        float v = (gh < H_DIM) ? acc[r][c] : -INFINITY;
        ins3(v, gh, v0, v1, v2, i0, i1, i2);
      }
      mv[(w * BN + col) * 3 + 0] = v0;
      mv[(w * BN + col) * 3 + 1] = v1;
      mv[(w * BN + col) * 3 + 2] = v2;
      mi[(w * BN + col) * 3 + 0] = i0;
      mi[(w * BN + col) * 3 + 1] = i1;
      mi[(w * BN + col) * 3 + 2] = i2;
    }
    __syncthreads();
    // threads 0..127: thread tid owns column tid; merge the 4 wave lists
    if (tid < BN) {
      const int col = tid;
#pragma unroll
      for (int ww = 0; ww < 4; ++ww)
#pragma unroll
        for (int j = 0; j < 3; ++j) {
          float v = mv[(ww * BN + col) * 3 + j];
          int   i = mi[(ww * BN + col) * 3 + j];
          ins3(v, i, gv0, gv1, gv2, gi0, gi1, gi2);
        }
    }
    __syncthreads();   // merge reads done before next rowtile overwrites
  }

  if (tid < BN) {
    int t = t0 + tid;
    if (t < T_DIM) {
      size_t base = ((size_t)(bc * nsplit + sp) * KTOP) * T_DIM + t;
      wv[base]             = gv0;
      wv[base + T_DIM]     = gv1;
      wv[base + 2 * T_DIM] = gv2;
      wi[base]             = gi0;
      wi[base + T_DIM]     = gi1;
      wi[base + 2 * T_DIM] = gi2;
    }
  }
}

// K3: merge the nsplit partial top-3 lists, causal-pool the indices, gather
// harmonic_loc rows, sum over K, threshold, write (B,C,F,T) coalesced.
__global__ __launch_bounds__(256, 4)
void hi_k3_pool_gather(const float* __restrict__ wv, const int* __restrict__ wi,
                       const float* __restrict__ hl, float* __restrict__ out,
                       int nsplit) {
  const int tid = threadIdx.x;
  const int t0 = blockIdx.x * 64;
  const int bc = blockIdx.y;

  __shared__ float pos_lds[66 * KTOP];   // t0-2 .. t0+63
  __shared__ int   rows[64 * KTOP];
  __shared__ float S[64 * 65];           // [t_local][f_chunk] transpose buffer

  if (tid < 66) {
    int t = t0 - 2 + tid;
    float p0 = PADV, p1 = PADV, p2 = PADV;
    if (t >= 0 && t < T_DIM) {
      float v0 = -INFINITY, v1 = -INFINITY, v2 = -INFINITY;
      int i0 = 0, i1 = 0, i2 = 0;
      for (int sp = 0; sp < nsplit; ++sp)        // ascending h ranges
        for (int j = 0; j < KTOP; ++j) {         // descending values
          size_t idx = ((size_t)(bc * nsplit + sp) * KTOP + j) * T_DIM + t;
          ins3(wv[idx], wi[idx], v0, v1, v2, i0, i1, i2);
        }
      p0 = (float)i0; p1 = (float)i1; p2 = (float)i2;
    }
    pos_lds[tid * KTOP + 0] = p0;
    pos_lds[tid * KTOP + 1] = p1;
    pos_lds[tid * KTOP + 2] = p2;
  }
  __syncthreads();
  if (tid < 64) {
#pragma unroll
    for (int k = 0; k < KTOP; ++k) {
      float s = (pos_lds[tid * KTOP + k] + pos_lds[(tid + 1) * KTOP + k])
                + pos_lds[(tid + 2) * KTOP + k];
      rows[tid * KTOP + k] = (int)(s / 3.0f);   // matches ref fp32 /3 + int cast
    }
  }
  __syncthreads();

  const int w = tid >> 6, lane = tid & 63;
  for (int fc = 0; fc < 6; ++fc) {
    const int f0 = fc * 64;
    for (int i = 0; i < 16; ++i) {
      int tl = w * 16 + i;
      int r0 = rows[tl * KTOP + 0];
      int r1 = rows[tl * KTOP + 1];
      int r2 = rows[tl * KTOP + 2];
      int f = f0 + lane;
      float s = 0.f;
      if (f < F_DIM)
        s = (hl[(size_t)r0 * F_DIM + f] + hl[(size_t)r1 * F_DIM + f])
            + hl[(size_t)r2 * F_DIM + f];
      S[tl * 65 + lane] = s;
    }
    __syncthreads();
#pragma unroll
    for (int i = 0; i < 16; ++i) {
      int e = tid + 256 * i;
      int fl = e >> 6, tl = e & 63;
      int f = f0 + fl, t = t0 + tl;
      if (f < F_DIM && t < T_DIM)
        out[((size_t)bc * F_DIM + f) * T_DIM + t] = (S[tl * 65 + fl] > 0.f) ? 1.f : 0.f;
    }
    __syncthreads();
  }
}

extern "C" void kernel_launch(void* const* d_in, const int* in_sizes, int n_in,
                              void* d_out, int out_size, void* d_ws, size_t ws_size,
                              hipStream_t stream) {
  const float* mag = (const float*)d_in[0];   // (8,2,321,1000)
  const float* im  = (const float*)d_in[1];   // (4200,321)
  const float* hl  = (const float*)d_in[2];   // (4200,321)
  float* out = (float*)d_out;                 // (8,2,321,1000)

  // pick largest nsplit the workspace can hold (8 is known-safe: 3.07 MB)
  int nsplit = 8;
  if (ws_size >= (size_t)NBC * 32 * KTOP * T_DIM * 8) nsplit = 32;       // 12.3 MB
  else if (ws_size >= (size_t)NBC * 16 * KTOP * T_DIM * 8) nsplit = 16;  // 6.1 MB
  float* wv = (float*)d_ws;
  int*   wi = (int*)d_ws + (size_t)NBC * nsplit * KTOP * T_DIM;

  dim3 g1(NTT, NBC, nsplit);   // 8 x 16 x nsplit blocks
  hipLaunchKernelGGL(hi_k1_gemm_top3, g1, dim3(256), 0, stream, mag, im, wv, wi, nsplit);

  dim3 g3((T_DIM + 63) / 64, NBC);               // 16 x 16 = 256 blocks
  hipLaunchKernelGGL(hi_k3_pool_gather, g3, dim3(256), 0, stream, wv, wi, hl, out, nsplit);
}

// Round 24
// 1242.662 us; speedup vs baseline: 1.2182x; 1.2182x over previous
//
#include <hip/hip_runtime.h>
#include <math.h>

// Problem constants
#define F_DIM 321
#define H_DIM 4200
#define T_DIM 1000
#define NBC   16      // B*C = 8*2
#define KTOP  3
#define PADV  1e-8f

// r24 = r22 geometry (4 waves x 8 rows, lane owns 4 cols, acc 8x4) with B
// moved from L1/L2 (64 B/cyc/CU ceiling -> VALU 58%) into LDS (256 B/clk).
// B staged once per block per k-tile via global_load_lds (r17-proven),
// counted-vmcnt double-buffer (r18-proven), A in SGPR dbuf (r22-proven).
// Per kt: LDS demand ~384 cyc (16 reads + 16 stage-writes) vs 512 VALU-wall
// per block -> VALU-bound with headroom. Merge aliases the drained Bs.
#define BM 32         // h rows per block tile (4 waves x 8)
#define BN 256        // t cols per block tile (64 lanes x 4)
#define BK 16
#define NRT 132       // ceil(H_DIM / BM)
#define NKT 20        // k-tiles of 16 covering k=0..319 (tail k=320 separate)
#define NGT 80        // total 4-k groups (A-dbuf index space)
#define NTT 4         // ceil(T_DIM / BN)

typedef float v4f __attribute__((ext_vector_type(4)));
typedef __attribute__((address_space(3))) uint32_t lds_u32;
typedef const __attribute__((address_space(1))) uint32_t glb_u32;

__device__ __forceinline__ void ins3(float v, int i,
                                     float& v0, float& v1, float& v2,
                                     int& i0, int& i1, int& i2) {
  // strict '>' keeps earlier (smaller-h) entries ahead on ties == lax.top_k
  if (v > v0)      { v2 = v1; i2 = i1; v1 = v0; i1 = i0; v0 = v; i0 = i; }
  else if (v > v1) { v2 = v1; i2 = i1; v1 = v;  i1 = i; }
  else if (v > v2) { v2 = v;  i2 = i; }
}

// read one 4-k B group from LDS buffer `buf` (4 k-rows x 4 cols/lane)
#define LOADBL(B0, B1, B2, B3, buf, g) do {                            \
    const float* _q = &Bs[buf][(g) * 4 * BN + lane * 4];               \
    B0 = *(const v4f*)(_q);                                            \
    B1 = *(const v4f*)(_q + BN);                                       \
    B2 = *(const v4f*)(_q + 2 * BN);                                   \
    B3 = *(const v4f*)(_q + 3 * BN);                                   \
  } while (0)

// load one 4-k A group (8 rows x 4 k, wave-uniform -> SGPR) into array D;
// gg is the GLOBAL group index 0..79
#define LOADA(D, gg) do {                                              \
    _Pragma("unroll") for (int r = 0; r < 8; ++r)                      \
      _Pragma("unroll") for (int q = 0; q < 4; ++q)                    \
        D[r][q] = im[ab[r] + (gg) * 4 + q];                            \
  } while (0)

// FMA one 4-k group from pre-loaded A array (k ascending per acc element)
#define FMAG(B0, B1, B2, B3, A) do {                                   \
    _Pragma("unroll") for (int r = 0; r < 8; ++r)                      \
      _Pragma("unroll") for (int c = 0; c < 4; ++c) {                  \
        acc[r][c] = fmaf(A[r][0], B0[c], acc[r][c]);                   \
        acc[r][c] = fmaf(A[r][1], B1[c], acc[r][c]);                   \
        acc[r][c] = fmaf(A[r][2], B2[c], acc[r][c]);                   \
        acc[r][c] = fmaf(A[r][3], B3[c], acc[r][c]);                   \
      }                                                                \
  } while (0)

// K1: fused fp32 GEMM (nominee = integral_m @ mag[bc]) + running top-3 over h.
__global__ __launch_bounds__(256)
void hi_k1_gemm_top3(const float* __restrict__ mag,
                     const float* __restrict__ im,
                     float* __restrict__ wv, int* __restrict__ wi,
                     int nsplit) {
  const int tid  = threadIdx.x;
  const int lane = tid & 63;
  const int w    = tid >> 6;      // wave index 0..3
  const int t0 = blockIdx.x * BN;
  const int bc = blockIdx.y;
  const int sp = blockIdx.z;
  const int rt_begin = (sp * NRT) / nsplit;
  const int rt_end   = ((sp + 1) * NRT) / nsplit;

  __shared__ __align__(16) float Bs[2][BK * BN];   // [k][t] dbuf, 16KB each
  // merge scratch aliases the drained double-buffer after the k-loop
  float* mv = (float*)&Bs[0][0];   // 4*256*3 = 3072 floats (12KB <= 16KB)
  int*   mi = (int*)&Bs[1][0];     // 3072 ints

  const float* magbc = mag + (size_t)bc * F_DIM * T_DIM;

  // stage B k-rows k0..k0+15 into Bs[buf]: 4 rows/wave, 1 wave-inst each
  // (row = 256 floats = 64 lanes x 16B, width=16, linear dest)
  auto stageB = [&](int buf, int k0) {
#pragma unroll
    for (int i = 0; i < 4; ++i) {
      int kr = w * 4 + i;
      const float* src = magbc + (size_t)(k0 + kr) * T_DIM + t0 + lane * 4;
      __builtin_amdgcn_global_load_lds(
          (glb_u32*)src, (lds_u32*)&Bs[buf][kr * BN], 16, 0, 0);
    }
  };
  // (t overrun of the last t-tile reads into the next k-row: max src index
  //  319*1000 + 1023 < 321*1000, in-bounds; those cols discarded at store.)

  float gv0 = -INFINITY, gv1 = -INFINITY, gv2 = -INFINITY;
  int   gi0 = 0, gi1 = 0, gi2 = 0;

  for (int rt = rt_begin; rt < rt_end; ++rt) {
    const int h0 = rt * BM;
    // wave-uniform row bases (SGPR); clamp dups masked at top-3
    int ab[8];
#pragma unroll
    for (int r = 0; r < 8; ++r) {
      int gh = h0 + w * 8 + r;
      if (gh >= H_DIM) gh = H_DIM - 1;
      ab[r] = __builtin_amdgcn_readfirstlane(gh * F_DIM);
    }

    float acc[8][4];
#pragma unroll
    for (int r = 0; r < 8; ++r)
#pragma unroll
      for (int c = 0; c < 4; ++c) acc[r][c] = 0.f;

    float Ac[8][4], An[8][4];
    v4f BA0, BA1, BA2, BA3, BB0, BB1, BB2, BB3;

    // prologue: 2 k-tiles in flight (8 stage insts); vmcnt(4) = tile 0 in
    stageB(0, 0);
    stageB(1, BK);
    LOADA(Ac, 0);
    asm volatile("s_waitcnt vmcnt(4)" ::: "memory");
    __builtin_amdgcn_s_barrier();
    __builtin_amdgcn_sched_barrier(0);

    int cur = 0;
    for (int kt = 0; kt < NKT; ++kt) {
      const int gg = kt * 4;   // global group index of this tile's group 0
      // 4 groups; A in SGPR dbuf one group ahead, B LDS-read dbuf within kt
      LOADBL(BA0, BA1, BA2, BA3, cur, 0);
      LOADA(An, gg + 1);
      LOADBL(BB0, BB1, BB2, BB3, cur, 1);
      FMAG(BA0, BA1, BA2, BA3, Ac);
      LOADA(Ac, gg + 2);
      LOADBL(BA0, BA1, BA2, BA3, cur, 2);
      FMAG(BB0, BB1, BB2, BB3, An);
      LOADA(An, gg + 3);
      LOADBL(BB0, BB1, BB2, BB3, cur, 3);
      FMAG(BA0, BA1, BA2, BA3, Ac);
      if (gg + 4 < NGT) LOADA(Ac, gg + 4);   // next kt's group 0 (guarded)
      FMAG(BB0, BB1, BB2, BB3, An);

      // barrier 1: all waves done reading Bs[cur]
      asm volatile("" ::: "memory");
      __builtin_amdgcn_s_barrier();
      __builtin_amdgcn_sched_barrier(0);

      if (kt + 2 < NKT) {
        stageB(cur, (kt + 2) * BK);
        // tile kt+1 landed (its 4 are oldest; kt+2's 4 stay in flight)
        asm volatile("s_waitcnt vmcnt(4)" ::: "memory");
      } else {
        asm volatile("s_waitcnt vmcnt(0)" ::: "memory");
      }
      // barrier 2: tile kt+1 fully in LDS
      asm volatile("" ::: "memory");
      __builtin_amdgcn_s_barrier();
      __builtin_amdgcn_sched_barrier(0);
      cur ^= 1;
    }

    // K tail: k = 320 (single column), guarded global loads
    {
      float bt[4];
#pragma unroll
      for (int c = 0; c < 4; ++c) {
        int gt = t0 + lane * 4 + c;
        bt[c] = (gt < T_DIM) ? magbc[(size_t)(F_DIM - 1) * T_DIM + gt] : 0.f;
      }
#pragma unroll
      for (int r = 0; r < 8; ++r) {
        float av = im[ab[r] + (F_DIM - 1)];
#pragma unroll
        for (int c = 0; c < 4; ++c) acc[r][c] = fmaf(av, bt[c], acc[r][c]);
      }
    }

    // thread-local top-3 per column over own 8 rows (h ascending); wave
    // bands ascend in w, so cross-wave merge preserves lax.top_k tie order.
    // Bs is drained (vmcnt(0) + barrier at k-loop end) -> alias as mv/mi.
#pragma unroll
    for (int c = 0; c < 4; ++c) {
      const int col = lane * 4 + c;
      float v0 = -INFINITY, v1 = -INFINITY, v2 = -INFINITY;
      int   i0 = 0, i1 = 0, i2 = 0;
#pragma unroll
      for (int r = 0; r < 8; ++r) {
        int gh = h0 + w * 8 + r;
        float v = (gh < H_DIM) ? acc[r][c] : -INFINITY;
        ins3(v, gh, v0, v1, v2, i0, i1, i2);
      }
      mv[(w * BN + col) * 3 + 0] = v0;
      mv[(w * BN + col) * 3 + 1] = v1;
      mv[(w * BN + col) * 3 + 2] = v2;
      mi[(w * BN + col) * 3 + 0] = i0;
      mi[(w * BN + col) * 3 + 1] = i1;
      mi[(w * BN + col) * 3 + 2] = i2;
    }
    __syncthreads();
    // thread tid owns column tid; merge the 4 wave lists (ascending h)
    {
      const int col = tid;
#pragma unroll
      for (int ww = 0; ww < 4; ++ww)
#pragma unroll
        for (int j = 0; j < 3; ++j) {
          float v = mv[(ww * BN + col) * 3 + j];
          int   i = mi[(ww * BN + col) * 3 + j];
          ins3(v, i, gv0, gv1, gv2, gi0, gi1, gi2);
        }
    }
    __syncthreads();   // merge reads done before next rowtile stages Bs
  }

  {
    int t = t0 + tid;
    if (t < T_DIM) {
      size_t base = ((size_t)(bc * nsplit + sp) * KTOP) * T_DIM + t;
      wv[base]             = gv0;
      wv[base + T_DIM]     = gv1;
      wv[base + 2 * T_DIM] = gv2;
      wi[base]             = gi0;
      wi[base + T_DIM]     = gi1;
      wi[base + 2 * T_DIM] = gi2;
    }
  }
}

// K3: merge the nsplit partial top-3 lists, causal-pool the indices, gather
// harmonic_loc rows, sum over K, threshold, write (B,C,F,T) coalesced.
__global__ __launch_bounds__(256, 4)
void hi_k3_pool_gather(const float* __restrict__ wv, const int* __restrict__ wi,
                       const float* __restrict__ hl, float* __restrict__ out,
                       int nsplit) {
  const int tid = threadIdx.x;
  const int t0 = blockIdx.x * 64;
  const int bc = blockIdx.y;

  __shared__ float pos_lds[66 * KTOP];   // t0-2 .. t0+63
  __shared__ int   rows[64 * KTOP];
  __shared__ float S[64 * 65];           // [t_local][f_chunk] transpose buffer

  if (tid < 66) {
    int t = t0 - 2 + tid;
    float p0 = PADV, p1 = PADV, p2 = PADV;
    if (t >= 0 && t < T_DIM) {
      float v0 = -INFINITY, v1 = -INFINITY, v2 = -INFINITY;
      int i0 = 0, i1 = 0, i2 = 0;
      for (int sp = 0; sp < nsplit; ++sp)        // ascending h ranges
        for (int j = 0; j < KTOP; ++j) {         // descending values
          size_t idx = ((size_t)(bc * nsplit + sp) * KTOP + j) * T_DIM + t;
          ins3(wv[idx], wi[idx], v0, v1, v2, i0, i1, i2);
        }
      p0 = (float)i0; p1 = (float)i1; p2 = (float)i2;
    }
    pos_lds[tid * KTOP + 0] = p0;
    pos_lds[tid * KTOP + 1] = p1;
    pos_lds[tid * KTOP + 2] = p2;
  }
  __syncthreads();
  if (tid < 64) {
#pragma unroll
    for (int k = 0; k < KTOP; ++k) {
      float s = (pos_lds[tid * KTOP + k] + pos_lds[(tid + 1) * KTOP + k])
                + pos_lds[(tid + 2) * KTOP + k];
      rows[tid * KTOP + k] = (int)(s / 3.0f);   // matches ref fp32 /3 + int cast
    }
  }
  __syncthreads();

  const int w = tid >> 6, lane = tid & 63;
  for (int fc = 0; fc < 6; ++fc) {
    const int f0 = fc * 64;
    for (int i = 0; i < 16; ++i) {
      int tl = w * 16 + i;
      int r0 = rows[tl * KTOP + 0];
      int r1 = rows[tl * KTOP + 1];
      int r2 = rows[tl * KTOP + 2];
      int f = f0 + lane;
      float s = 0.f;
      if (f < F_DIM)
        s = (hl[(size_t)r0 * F_DIM + f] + hl[(size_t)r1 * F_DIM + f])
            + hl[(size_t)r2 * F_DIM + f];
      S[tl * 65 + lane] = s;
    }
    __syncthreads();
#pragma unroll
    for (int i = 0; i < 16; ++i) {
      int e = tid + 256 * i;
      int fl = e >> 6, tl = e & 63;
      int f = f0 + fl, t = t0 + tl;
      if (f < F_DIM && t < T_DIM)
        out[((size_t)bc * F_DIM + f) * T_DIM + t] = (S[tl * 65 + fl] > 0.f) ? 1.f : 0.f;
    }
    __syncthreads();
  }
}

extern "C" void kernel_launch(void* const* d_in, const int* in_sizes, int n_in,
                              void* d_out, int out_size, void* d_ws, size_t ws_size,
                              hipStream_t stream) {
  const float* mag = (const float*)d_in[0];   // (8,2,321,1000)
  const float* im  = (const float*)d_in[1];   // (4200,321)
  const float* hl  = (const float*)d_in[2];   // (4200,321)
  float* out = (float*)d_out;                 // (8,2,321,1000)

  // pick largest nsplit the workspace can hold (8 is known-safe: 3.07 MB)
  int nsplit = 8;
  if (ws_size >= (size_t)NBC * 32 * KTOP * T_DIM * 8) nsplit = 32;       // 12.3 MB
  else if (ws_size >= (size_t)NBC * 16 * KTOP * T_DIM * 8) nsplit = 16;  // 6.1 MB
  float* wv = (float*)d_ws;
  int*   wi = (int*)d_ws + (size_t)NBC * nsplit * KTOP * T_DIM;

  dim3 g1(NTT, NBC, nsplit);   // 4 x 16 x nsplit blocks
  hipLaunchKernelGGL(hi_k1_gemm_top3, g1, dim3(256), 0, stream, mag, im, wv, wi, nsplit);

  dim3 g3((T_DIM + 63) / 64, NBC);               // 16 x 16 = 256 blocks
  hipLaunchKernelGGL(hi_k3_pool_gather, g3, dim3(256), 0, stream, wv, wi, hl, out, nsplit);
}

// Round 25
// 1134.653 us; speedup vs baseline: 1.3342x; 1.0952x over previous
//
#include <hip/hip_runtime.h>
#include <math.h>

// Problem constants
#define F_DIM 321
#define H_DIM 4200
#define T_DIM 1000
#define NBC   16      // B*C = 8*2
#define KTOP  3
#define PADV  1e-8f

// r25 = r22 (best: zero-LDS/zero-barrier loop, A in SGPR dbuf, B reg-dbuf
// from L1) with BN 256->128 to DOUBLE the grid. r22 evidence: VGPR=64 (8
// waves/SIMD possible) but occupancy only 36% -- grid-starved at 4 t-tiles.
// FMA is ~90% of VALU issue; the 42% idle is latency stall -> more resident
// waves is the remaining lever. B delivery per FMA unchanged (0.5 B/lane).
#define BM 32         // h rows per block tile (4 waves x 8)
#define BN 128        // t cols per block tile (64 lanes x 2)
#define NRT 132       // ceil(H_DIM / BM)
#define NG  80        // 4-k groups covering k=0..319 (tail k=320 separate)
#define NTT 8         // ceil(T_DIM / BN)

typedef float v2f __attribute__((ext_vector_type(2)));

__device__ __forceinline__ void ins3(float v, int i,
                                     float& v0, float& v1, float& v2,
                                     int& i0, int& i1, int& i2) {
  // strict '>' keeps earlier (smaller-h) entries ahead on ties == lax.top_k
  if (v > v0)      { v2 = v1; i2 = i1; v1 = v0; i1 = i0; v0 = v; i0 = i; }
  else if (v > v1) { v2 = v1; i2 = i1; v1 = v;  i1 = i; }
  else if (v > v2) { v2 = v;  i2 = i; }
}

// load one 4-k B group (4 k-rows x 2 cols/lane) into 4 named v2f regs
#define LOADB(B0, B1, B2, B3, g) do {                                  \
    const float* _p = pB + (size_t)((g) * 4) * T_DIM;                  \
    B0 = *(const v2f*)(_p);                                            \
    B1 = *(const v2f*)(_p + T_DIM);                                    \
    B2 = *(const v2f*)(_p + 2 * T_DIM);                                \
    B3 = *(const v2f*)(_p + 3 * T_DIM);                                \
  } while (0)

// load one 4-k A group (8 rows x 4 k, wave-uniform -> SGPR) into array D
#define LOADA(D, g) do {                                               \
    _Pragma("unroll") for (int r = 0; r < 8; ++r)                      \
      _Pragma("unroll") for (int q = 0; q < 4; ++q)                    \
        D[r][q] = im[ab[r] + (g) * 4 + q];                             \
  } while (0)

// FMA one 4-k group from pre-loaded A array (k ascending per acc element)
#define FMAG(B0, B1, B2, B3, A) do {                                   \
    _Pragma("unroll") for (int r = 0; r < 8; ++r)                      \
      _Pragma("unroll") for (int c = 0; c < 2; ++c) {                  \
        acc[r][c] = fmaf(A[r][0], B0[c], acc[r][c]);                   \
        acc[r][c] = fmaf(A[r][1], B1[c], acc[r][c]);                   \
        acc[r][c] = fmaf(A[r][2], B2[c], acc[r][c]);                   \
        acc[r][c] = fmaf(A[r][3], B3[c], acc[r][c]);                   \
      }                                                                \
  } while (0)

// K1: fused fp32 GEMM (nominee = integral_m @ mag[bc]) + running top-3 over h.
__global__ __launch_bounds__(256)
void hi_k1_gemm_top3(const float* __restrict__ mag,
                     const float* __restrict__ im,
                     float* __restrict__ wv, int* __restrict__ wi,
                     int nsplit) {
  const int tid  = threadIdx.x;
  const int lane = tid & 63;
  const int w    = tid >> 6;      // wave index 0..3
  const int t0 = blockIdx.x * BN;
  const int bc = blockIdx.y;
  const int sp = blockIdx.z;
  const int rt_begin = (sp * NRT) / nsplit;
  const int rt_end   = ((sp + 1) * NRT) / nsplit;

  __shared__ float mv[4 * BN * KTOP];   // merge scratch only (6 KB)
  __shared__ int   mi[4 * BN * KTOP];   // (6 KB)

  const float* magbc = mag + (size_t)bc * F_DIM * T_DIM;
  const float* pB = magbc + t0 + lane * 2;   // per-lane B column base
  // (t overrun of the last t-tile reads into the next k-row: max src index
  //  319*1000 + 1023 < 321*1000, in-bounds; those cols discarded at store.)

  float gv0 = -INFINITY, gv1 = -INFINITY, gv2 = -INFINITY;
  int   gi0 = 0, gi1 = 0, gi2 = 0;

  for (int rt = rt_begin; rt < rt_end; ++rt) {
    const int h0 = rt * BM;
    // wave-uniform row bases (SGPR); clamp dups masked at top-3
    int ab[8];
#pragma unroll
    for (int r = 0; r < 8; ++r) {
      int gh = h0 + w * 8 + r;
      if (gh >= H_DIM) gh = H_DIM - 1;
      ab[r] = __builtin_amdgcn_readfirstlane(gh * F_DIM);
    }

    float acc[8][2];
#pragma unroll
    for (int r = 0; r < 8; ++r) { acc[r][0] = 0.f; acc[r][1] = 0.f; }

    float Ac[8][4], An[8][4];
    v2f Bc0, Bc1, Bc2, Bc3, Bn0, Bn1, Bn2, Bn3;
    LOADA(Ac, 0);
    LOADB(Bc0, Bc1, Bc2, Bc3, 0);

    // 40 double-steps cover g=0..79 (k=0..319). Both operands register-
    // double-buffered one group ahead; no LDS, no barriers in the k-loop.
#pragma unroll 1
    for (int gs = 0; gs < NG / 2; ++gs) {
      const int ge = 2 * gs, go = 2 * gs + 1;
      LOADA(An, go);
      LOADB(Bn0, Bn1, Bn2, Bn3, go);          // go <= 79 always
      FMAG(Bc0, Bc1, Bc2, Bc3, Ac);
      if (ge + 2 < NG) {
        LOADA(Ac, ge + 2);
        LOADB(Bc0, Bc1, Bc2, Bc3, ge + 2);
      }
      FMAG(Bn0, Bn1, Bn2, Bn3, An);
    }

    // K tail: k = 320 (single column), guarded loads
    {
      float bt[2];
#pragma unroll
      for (int c = 0; c < 2; ++c) {
        int gt = t0 + lane * 2 + c;
        bt[c] = (gt < T_DIM) ? magbc[(size_t)(F_DIM - 1) * T_DIM + gt] : 0.f;
      }
#pragma unroll
      for (int r = 0; r < 8; ++r) {
        float av = im[ab[r] + (F_DIM - 1)];
        acc[r][0] = fmaf(av, bt[0], acc[r][0]);
        acc[r][1] = fmaf(av, bt[1], acc[r][1]);
      }
    }

    // thread-local top-3 per column over own 8 rows (h ascending); wave
    // bands ascend in w, so cross-wave merge preserves lax.top_k tie order.
#pragma unroll
    for (int c = 0; c < 2; ++c) {
      const int col = lane * 2 + c;
      float v0 = -INFINITY, v1 = -INFINITY, v2 = -INFINITY;
      int   i0 = 0, i1 = 0, i2 = 0;
#pragma unroll
      for (int r = 0; r < 8; ++r) {
        int gh = h0 + w * 8 + r;
        float v = (gh < H_DIM) ? acc[r][c] : -INFINITY;
        ins3(v, gh, v0, v1, v2, i0, i1, i2);
      }
      mv[(w * BN + col) * 3 + 0] = v0;
      mv[(w * BN + col) * 3 + 1] = v1;
      mv[(w * BN + col) * 3 + 2] = v2;
      mi[(w * BN + col) * 3 + 0] = i0;
      mi[(w * BN + col) * 3 + 1] = i1;
      mi[(w * BN + col) * 3 + 2] = i2;
    }
    __syncthreads();
    // threads 0..127: thread tid owns column tid; merge the 4 wave lists
    if (tid < BN) {
      const int col = tid;
#pragma unroll
      for (int ww = 0; ww < 4; ++ww)
#pragma unroll
        for (int j = 0; j < 3; ++j) {
          float v = mv[(ww * BN + col) * 3 + j];
          int   i = mi[(ww * BN + col) * 3 + j];
          ins3(v, i, gv0, gv1, gv2, gi0, gi1, gi2);
        }
    }
    __syncthreads();   // merge reads done before next rowtile overwrites
  }

  if (tid < BN) {
    int t = t0 + tid;
    if (t < T_DIM) {
      size_t base = ((size_t)(bc * nsplit + sp) * KTOP) * T_DIM + t;
      wv[base]             = gv0;
      wv[base + T_DIM]     = gv1;
      wv[base + 2 * T_DIM] = gv2;
      wi[base]             = gi0;
      wi[base + T_DIM]     = gi1;
      wi[base + 2 * T_DIM] = gi2;
    }
  }
}

// K3: merge the nsplit partial top-3 lists, causal-pool the indices, gather
// harmonic_loc rows, sum over K, threshold, write (B,C,F,T) coalesced.
__global__ __launch_bounds__(256, 4)
void hi_k3_pool_gather(const float* __restrict__ wv, const int* __restrict__ wi,
                       const float* __restrict__ hl, float* __restrict__ out,
                       int nsplit) {
  const int tid = threadIdx.x;
  const int t0 = blockIdx.x * 64;
  const int bc = blockIdx.y;

  __shared__ float pos_lds[66 * KTOP];   // t0-2 .. t0+63
  __shared__ int   rows[64 * KTOP];
  __shared__ float S[64 * 65];           // [t_local][f_chunk] transpose buffer

  if (tid < 66) {
    int t = t0 - 2 + tid;
    float p0 = PADV, p1 = PADV, p2 = PADV;
    if (t >= 0 && t < T_DIM) {
      float v0 = -INFINITY, v1 = -INFINITY, v2 = -INFINITY;
      int i0 = 0, i1 = 0, i2 = 0;
      for (int sp = 0; sp < nsplit; ++sp)        // ascending h ranges
        for (int j = 0; j < KTOP; ++j) {         // descending values
          size_t idx = ((size_t)(bc * nsplit + sp) * KTOP + j) * T_DIM + t;
          ins3(wv[idx], wi[idx], v0, v1, v2, i0, i1, i2);
        }
      p0 = (float)i0; p1 = (float)i1; p2 = (float)i2;
    }
    pos_lds[tid * KTOP + 0] = p0;
    pos_lds[tid * KTOP + 1] = p1;
    pos_lds[tid * KTOP + 2] = p2;
  }
  __syncthreads();
  if (tid < 64) {
#pragma unroll
    for (int k = 0; k < KTOP; ++k) {
      float s = (pos_lds[tid * KTOP + k] + pos_lds[(tid + 1) * KTOP + k])
                + pos_lds[(tid + 2) * KTOP + k];
      rows[tid * KTOP + k] = (int)(s / 3.0f);   // matches ref fp32 /3 + int cast
    }
  }
  __syncthreads();

  const int w = tid >> 6, lane = tid & 63;
  for (int fc = 0; fc < 6; ++fc) {
    const int f0 = fc * 64;
    for (int i = 0; i < 16; ++i) {
      int tl = w * 16 + i;
      int r0 = rows[tl * KTOP + 0];
      int r1 = rows[tl * KTOP + 1];
      int r2 = rows[tl * KTOP + 2];
      int f = f0 + lane;
      float s = 0.f;
      if (f < F_DIM)
        s = (hl[(size_t)r0 * F_DIM + f] + hl[(size_t)r1 * F_DIM + f])
            + hl[(size_t)r2 * F_DIM + f];
      S[tl * 65 + lane] = s;
    }
    __syncthreads();
#pragma unroll
    for (int i = 0; i < 16; ++i) {
      int e = tid + 256 * i;
      int fl = e >> 6, tl = e & 63;
      int f = f0 + fl, t = t0 + tl;
      if (f < F_DIM && t < T_DIM)
        out[((size_t)bc * F_DIM + f) * T_DIM + t] = (S[tl * 65 + fl] > 0.f) ? 1.f : 0.f;
    }
    __syncthreads();
  }
}

extern "C" void kernel_launch(void* const* d_in, const int* in_sizes, int n_in,
                              void* d_out, int out_size, void* d_ws, size_t ws_size,
                              hipStream_t stream) {
  const float* mag = (const float*)d_in[0];   // (8,2,321,1000)
  const float* im  = (const float*)d_in[1];   // (4200,321)
  const float* hl  = (const float*)d_in[2];   // (4200,321)
  float* out = (float*)d_out;                 // (8,2,321,1000)

  // pick largest nsplit the workspace can hold (8 is known-safe: 3.07 MB)
  int nsplit = 8;
  if (ws_size >= (size_t)NBC * 32 * KTOP * T_DIM * 8) nsplit = 32;       // 12.3 MB
  else if (ws_size >= (size_t)NBC * 16 * KTOP * T_DIM * 8) nsplit = 16;  // 6.1 MB
  float* wv = (float*)d_ws;
  int*   wi = (int*)d_ws + (size_t)NBC * nsplit * KTOP * T_DIM;

  dim3 g1(NTT, NBC, nsplit);   // 8 x 16 x nsplit blocks
  hipLaunchKernelGGL(hi_k1_gemm_top3, g1, dim3(256), 0, stream, mag, im, wv, wi, nsplit);

  dim3 g3((T_DIM + 63) / 64, NBC);               // 16 x 16 = 256 blocks
  hipLaunchKernelGGL(hi_k3_pool_gather, g3, dim3(256), 0, stream, wv, wi, hl, out, nsplit);
}

// Round 26
// 911.966 us; speedup vs baseline: 1.6599x; 1.2442x over previous
//
#include <hip/hip_runtime.h>
#include <math.h>

// Problem constants
#define F_DIM 321
#define H_DIM 4200
#define T_DIM 1000
#define NBC   16      // B*C = 8*2
#define KTOP  3
#define PADV  1e-8f

// r26 = r22 verbatim (best measured: 910us total, K1 ~940us, VALU 58%,
// VGPR 64, absmax 0). Design: zero-LDS zero-barrier k-loop; wave owns 8
// rows x 256 cols; lane owns 8r x 4c (acc 32); A wave-uniform -> SGPR
// double-buffer (readfirstlane-forced); B register double-buffer straight
// from global (L1-hot, 4-way ty broadcast across the block's waves).
// 15 structural variants (r12-r25: staging x4, sync x3, occupancy x3,
// operand-path x4, reuse-geometry x3) all landed 3-60% worse; (8 rows,
// 4 cols) maximizes FMA-amortization x delivery-BW x occupancy.
#define BM 32         // h rows per block tile (4 waves x 8)
#define BN 256        // t cols per block tile (64 lanes x 4)
#define NRT 132       // ceil(H_DIM / BM)
#define NG  80        // 4-k groups covering k=0..319 (tail k=320 separate)
#define NTT 4         // ceil(T_DIM / BN)

typedef float v4f __attribute__((ext_vector_type(4)));

__device__ __forceinline__ void ins3(float v, int i,
                                     float& v0, float& v1, float& v2,
                                     int& i0, int& i1, int& i2) {
  // strict '>' keeps earlier (smaller-h) entries ahead on ties == lax.top_k
  if (v > v0)      { v2 = v1; i2 = i1; v1 = v0; i1 = i0; v0 = v; i0 = i; }
  else if (v > v1) { v2 = v1; i2 = i1; v1 = v;  i1 = i; }
  else if (v > v2) { v2 = v;  i2 = i; }
}

// load one 4-k B group (4 rows x 4 cols/lane) into 4 named v4f regs
#define LOADB(B0, B1, B2, B3, g) do {                                  \
    const float* _p = pB + (size_t)((g) * 4) * T_DIM;                  \
    B0 = *(const v4f*)(_p);                                            \
    B1 = *(const v4f*)(_p + T_DIM);                                    \
    B2 = *(const v4f*)(_p + 2 * T_DIM);                                \
    B3 = *(const v4f*)(_p + 3 * T_DIM);                                \
  } while (0)

// load one 4-k A group (8 rows x 4 k, wave-uniform) into named array D
#define LOADA(D, g) do {                                               \
    _Pragma("unroll") for (int r = 0; r < 8; ++r)                      \
      _Pragma("unroll") for (int q = 0; q < 4; ++q)                    \
        D[r][q] = im[ab[r] + (g) * 4 + q];                             \
  } while (0)

// FMA one 4-k group from pre-loaded A array (k ascending per acc element)
#define FMAG(B0, B1, B2, B3, A) do {                                   \
    _Pragma("unroll") for (int r = 0; r < 8; ++r)                      \
      _Pragma("unroll") for (int c = 0; c < 4; ++c) {                  \
        acc[r][c] = fmaf(A[r][0], B0[c], acc[r][c]);                   \
        acc[r][c] = fmaf(A[r][1], B1[c], acc[r][c]);                   \
        acc[r][c] = fmaf(A[r][2], B2[c], acc[r][c]);                   \
        acc[r][c] = fmaf(A[r][3], B3[c], acc[r][c]);                   \
      }                                                                \
  } while (0)

// K1: fused fp32 GEMM (nominee = integral_m @ mag[bc]) + running top-3 over h.
__global__ __launch_bounds__(256)
void hi_k1_gemm_top3(const float* __restrict__ mag,
                     const float* __restrict__ im,
                     float* __restrict__ wv, int* __restrict__ wi,
                     int nsplit) {
  const int tid  = threadIdx.x;
  const int lane = tid & 63;
  const int w    = tid >> 6;      // wave index 0..3
  const int t0 = blockIdx.x * BN;
  const int bc = blockIdx.y;
  const int sp = blockIdx.z;
  const int rt_begin = (sp * NRT) / nsplit;
  const int rt_end   = ((sp + 1) * NRT) / nsplit;

  __shared__ float mv[4 * BN * KTOP];   // merge scratch only (12 KB)
  __shared__ int   mi[4 * BN * KTOP];   // (12 KB)

  const float* magbc = mag + (size_t)bc * F_DIM * T_DIM;
  const float* pB = magbc + t0 + lane * 4;   // per-lane B column base
  // (t overrun of the last t-tile reads into the next k-row: in-bounds for
  //  k<=319, and those columns are discarded at store time)

  float gv0 = -INFINITY, gv1 = -INFINITY, gv2 = -INFINITY;
  int   gi0 = 0, gi1 = 0, gi2 = 0;

  for (int rt = rt_begin; rt < rt_end; ++rt) {
    const int h0 = rt * BM;
    // wave-uniform row bases (SGPR); clamp dups masked at top-3
    int ab[8];
#pragma unroll
    for (int r = 0; r < 8; ++r) {
      int gh = h0 + w * 8 + r;
      if (gh >= H_DIM) gh = H_DIM - 1;
      ab[r] = __builtin_amdgcn_readfirstlane(gh * F_DIM);
    }

    float acc[8][4];
#pragma unroll
    for (int r = 0; r < 8; ++r)
#pragma unroll
      for (int c = 0; c < 4; ++c) acc[r][c] = 0.f;

    float Ac[8][4], An[8][4];
    v4f Bc0, Bc1, Bc2, Bc3, Bn0, Bn1, Bn2, Bn3;
    LOADA(Ac, 0);
    LOADB(Bc0, Bc1, Bc2, Bc3, 0);

    // 40 double-steps cover g=0..79 (k=0..319). Both operands register-
    // double-buffered one group ahead; no LDS, no barriers; per-wave
    // waitcnts overlap the other buffer's 256-cycle FMA block.
#pragma unroll 1
    for (int gs = 0; gs < NG / 2; ++gs) {
      const int ge = 2 * gs, go = 2 * gs + 1;
      LOADA(An, go);
      LOADB(Bn0, Bn1, Bn2, Bn3, go);          // go <= 79 always
      FMAG(Bc0, Bc1, Bc2, Bc3, Ac);
      if (ge + 2 < NG) {
        LOADA(Ac, ge + 2);
        LOADB(Bc0, Bc1, Bc2, Bc3, ge + 2);
      }
      FMAG(Bn0, Bn1, Bn2, Bn3, An);
    }

    // K tail: k = 320 (single column), guarded loads
    {
      float bt[4];
#pragma unroll
      for (int c = 0; c < 4; ++c) {
        int gt = t0 + lane * 4 + c;
        bt[c] = (gt < T_DIM) ? magbc[(size_t)(F_DIM - 1) * T_DIM + gt] : 0.f;
      }
#pragma unroll
      for (int r = 0; r < 8; ++r) {
        float av = im[ab[r] + (F_DIM - 1)];
#pragma unroll
        for (int c = 0; c < 4; ++c) acc[r][c] = fmaf(av, bt[c], acc[r][c]);
      }
    }

    // thread-local top-3 per column over own 8 rows (h ascending); wave
    // bands ascend in w, so cross-wave merge preserves lax.top_k tie order.
#pragma unroll
    for (int c = 0; c < 4; ++c) {
      const int col = lane * 4 + c;
      float v0 = -INFINITY, v1 = -INFINITY, v2 = -INFINITY;
      int   i0 = 0, i1 = 0, i2 = 0;
#pragma unroll
      for (int r = 0; r < 8; ++r) {
        int gh = h0 + w * 8 + r;
        float v = (gh < H_DIM) ? acc[r][c] : -INFINITY;
        ins3(v, gh, v0, v1, v2, i0, i1, i2);
      }
      mv[(w * BN + col) * 3 + 0] = v0;
      mv[(w * BN + col) * 3 + 1] = v1;
      mv[(w * BN + col) * 3 + 2] = v2;
      mi[(w * BN + col) * 3 + 0] = i0;
      mi[(w * BN + col) * 3 + 1] = i1;
      mi[(w * BN + col) * 3 + 2] = i2;
    }
    __syncthreads();
    // thread tid owns column tid; merge the 4 wave lists (ascending h)
    {
      const int col = tid;
#pragma unroll
      for (int ww = 0; ww < 4; ++ww)
#pragma unroll
        for (int j = 0; j < 3; ++j) {
          float v = mv[(ww * BN + col) * 3 + j];
          int   i = mi[(ww * BN + col) * 3 + j];
          ins3(v, i, gv0, gv1, gv2, gi0, gi1, gi2);
        }
    }
    __syncthreads();   // merge reads done before next rowtile overwrites
  }

  {
    int t = t0 + tid;
    if (t < T_DIM) {
      size_t base = ((size_t)(bc * nsplit + sp) * KTOP) * T_DIM + t;
      wv[base]             = gv0;
      wv[base + T_DIM]     = gv1;
      wv[base + 2 * T_DIM] = gv2;
      wi[base]             = gi0;
      wi[base + T_DIM]     = gi1;
      wi[base + 2 * T_DIM] = gi2;
    }
  }
}

// K3: merge the nsplit partial top-3 lists, causal-pool the indices, gather
// harmonic_loc rows, sum over K, threshold, write (B,C,F,T) coalesced.
__global__ __launch_bounds__(256, 4)
void hi_k3_pool_gather(const float* __restrict__ wv, const int* __restrict__ wi,
                       const float* __restrict__ hl, float* __restrict__ out,
                       int nsplit) {
  const int tid = threadIdx.x;
  const int t0 = blockIdx.x * 64;
  const int bc = blockIdx.y;

  __shared__ float pos_lds[66 * KTOP];   // t0-2 .. t0+63
  __shared__ int   rows[64 * KTOP];
  __shared__ float S[64 * 65];           // [t_local][f_chunk] transpose buffer

  if (tid < 66) {
    int t = t0 - 2 + tid;
    float p0 = PADV, p1 = PADV, p2 = PADV;
    if (t >= 0 && t < T_DIM) {
      float v0 = -INFINITY, v1 = -INFINITY, v2 = -INFINITY;
      int i0 = 0, i1 = 0, i2 = 0;
      for (int sp = 0; sp < nsplit; ++sp)        // ascending h ranges
        for (int j = 0; j < KTOP; ++j) {         // descending values
          size_t idx = ((size_t)(bc * nsplit + sp) * KTOP + j) * T_DIM + t;
          ins3(wv[idx], wi[idx], v0, v1, v2, i0, i1, i2);
        }
      p0 = (float)i0; p1 = (float)i1; p2 = (float)i2;
    }
    pos_lds[tid * KTOP + 0] = p0;
    pos_lds[tid * KTOP + 1] = p1;
    pos_lds[tid * KTOP + 2] = p2;
  }
  __syncthreads();
  if (tid < 64) {
#pragma unroll
    for (int k = 0; k < KTOP; ++k) {
      float s = (pos_lds[tid * KTOP + k] + pos_lds[(tid + 1) * KTOP + k])
                + pos_lds[(tid + 2) * KTOP + k];
      rows[tid * KTOP + k] = (int)(s / 3.0f);   // matches ref fp32 /3 + int cast
    }
  }
  __syncthreads();

  const int w = tid >> 6, lane = tid & 63;
  for (int fc = 0; fc < 6; ++fc) {
    const int f0 = fc * 64;
    for (int i = 0; i < 16; ++i) {
      int tl = w * 16 + i;
      int r0 = rows[tl * KTOP + 0];
      int r1 = rows[tl * KTOP + 1];
      int r2 = rows[tl * KTOP + 2];
      int f = f0 + lane;
      float s = 0.f;
      if (f < F_DIM)
        s = (hl[(size_t)r0 * F_DIM + f] + hl[(size_t)r1 * F_DIM + f])
            + hl[(size_t)r2 * F_DIM + f];
      S[tl * 65 + lane] = s;
    }
    __syncthreads();
#pragma unroll
    for (int i = 0; i < 16; ++i) {
      int e = tid + 256 * i;
      int fl = e >> 6, tl = e & 63;
      int f = f0 + fl, t = t0 + tl;
      if (f < F_DIM && t < T_DIM)
        out[((size_t)bc * F_DIM + f) * T_DIM + t] = (S[tl * 65 + fl] > 0.f) ? 1.f : 0.f;
    }
    __syncthreads();
  }
}

extern "C" void kernel_launch(void* const* d_in, const int* in_sizes, int n_in,
                              void* d_out, int out_size, void* d_ws, size_t ws_size,
                              hipStream_t stream) {
  const float* mag = (const float*)d_in[0];   // (8,2,321,1000)
  const float* im  = (const float*)d_in[1];   // (4200,321)
  const float* hl  = (const float*)d_in[2];   // (4200,321)
  float* out = (float*)d_out;                 // (8,2,321,1000)

  // pick largest nsplit the workspace can hold (8 is known-safe: 3.07 MB)
  int nsplit = 8;
  if (ws_size >= (size_t)NBC * 32 * KTOP * T_DIM * 8) nsplit = 32;       // 12.3 MB
  else if (ws_size >= (size_t)NBC * 16 * KTOP * T_DIM * 8) nsplit = 16;  // 6.1 MB
  float* wv = (float*)d_ws;
  int*   wi = (int*)d_ws + (size_t)NBC * nsplit * KTOP * T_DIM;

  dim3 g1(NTT, NBC, nsplit);   // 4 x 16 x nsplit blocks
  hipLaunchKernelGGL(hi_k1_gemm_top3, g1, dim3(256), 0, stream, mag, im, wv, wi, nsplit);

  dim3 g3((T_DIM + 63) / 64, NBC);               // 16 x 16 = 256 blocks
  hipLaunchKernelGGL(hi_k3_pool_gather, g3, dim3(256), 0, stream, wv, wi, hl, out, nsplit);
}